// Round 4
// baseline (673.549 us; speedup 1.0000x reference)
//
#include <hip/hip_runtime.h>

#define N_NODES 50000
#define NUM_P   20000
#define D_DIM   128
#define ALPHA_  0.2f
#define EPS_    1e-12f

// L2-norm inverse over the 128 threads (2 waves) of the block.
__device__ __forceinline__ float block_rownorm_inv(float y, float* wsum) {
    float s = y * y;
    #pragma unroll
    for (int o = 32; o > 0; o >>= 1) s += __shfl_xor(s, o);
    if ((threadIdx.x & 63) == 0) wsum[threadIdx.x >> 6] = s;
    __syncthreads();
    const float tot = wsum[0] + wsum[1];
    return 1.0f / fmaxf(sqrtf(tot), EPS_);
}

// ---------------------------------------------------------------------------
// SAGE: out0[node] = l2norm(leaky([x[node] | mean_k x[idx[node,k]]] @ W))
// One node per 128-thread block. SPLIT: source row r < NUM_P -> srcLow else srcHigh.
// out1 (optional): also write rows >= NUM_P there (feat tail).
// ---------------------------------------------------------------------------
template<int K, bool SPLIT>
__global__ __launch_bounds__(128)
void sage_f32(const float* __restrict__ srcLow,
              const float* __restrict__ srcHigh,
              const int*   __restrict__ idx,
              const float* __restrict__ W,      // [2D][D] row-major
              float* __restrict__ out0,
              float* __restrict__ out1)
{
    __shared__ float xs[2 * D_DIM];
    __shared__ float wsum[2];

    const int node = blockIdx.x;
    const int d    = threadIdx.x;
    const size_t off = (size_t)node * D_DIM + d;

    const float* sp = (!SPLIT || node < NUM_P) ? srcLow : srcHigh;
    const float self = sp[off];

    const int* ir = idx + (size_t)node * K;
    float acc = 0.f;
    for (int k = 0; k < K; ++k) {
        const int r = ir[k];
        const float* rp = (!SPLIT || r < NUM_P) ? srcLow : srcHigh;
        acc += rp[(size_t)r * D_DIM + d];
    }

    xs[d]         = self;
    xs[D_DIM + d] = acc * (1.0f / K);
    __syncthreads();

    // y[d] = sum_c xs[c] * W[c][d]  (xs[c] LDS broadcast; W row coalesced)
    float y = 0.f;
    for (int c = 0; c < 2 * D_DIM; ++c)
        y = fmaf(xs[c], W[(size_t)c * D_DIM + d], y);

    y = y > 0.f ? y : ALPHA_ * y;

    const float inv = block_rownorm_inv(y, wsum);
    const float v = y * inv;
    out0[off] = v;
    if (out1 != nullptr && node >= NUM_P) out1[off] = v;
}

// ---------------------------------------------------------------------------
// Temporal: out[n] = l2norm(leaky([head[n] | ((mean_p hist[p,n]) @ Whis)] @ WT))
// One node per 128-thread block, nodes < NUM_P.
// ---------------------------------------------------------------------------
__global__ __launch_bounds__(128)
void temporal_f32(const float* __restrict__ head,   // rows < NUM_P used
                  const float* __restrict__ hist,   // [3][NUM_P][D]
                  const float* __restrict__ Whis,   // [D][D]
                  const float* __restrict__ WT,     // [2D][D]
                  float* __restrict__ outp)
{
    __shared__ float xs[2 * D_DIM];
    __shared__ float hmean[D_DIM];
    __shared__ float wsum[2];

    const int node = blockIdx.x;
    const int d    = threadIdx.x;
    const size_t HS  = (size_t)NUM_P * D_DIM;
    const size_t off = (size_t)node * D_DIM + d;

    xs[d]    = head[off];
    hmean[d] = (hist[off] + hist[off + HS] + hist[off + 2 * HS]) * (1.0f / 3.0f);
    __syncthreads();

    // tf[d] = sum_c hmean[c] * Whis[c][d]
    float tf = 0.f;
    for (int c = 0; c < D_DIM; ++c)
        tf = fmaf(hmean[c], Whis[(size_t)c * D_DIM + d], tf);
    xs[D_DIM + d] = tf;
    __syncthreads();

    // y[d] = sum_c xs[c] * WT[c][d]
    float y = 0.f;
    for (int c = 0; c < 2 * D_DIM; ++c)
        y = fmaf(xs[c], WT[(size_t)c * D_DIM + d], y);

    y = y > 0.f ? y : ALPHA_ * y;

    const float inv = block_rownorm_inv(y, wsum);
    outp[off] = y * inv;
}

// ---------------------------------------------------------------------------
extern "C" void kernel_launch(void* const* d_in, const int* in_sizes, int n_in,
                              void* d_out, int out_size, void* d_ws, size_t ws_size,
                              hipStream_t stream)
{
    (void)in_sizes; (void)n_in; (void)out_size; (void)d_ws; (void)ws_size;

    const float* feats = (const float*)d_in[0];
    const int*   idx1  = (const int*)  d_in[1];
    const int*   idx2  = (const int*)  d_in[2];
    const float* hist1 = (const float*)d_in[3];
    const float* hist2 = (const float*)d_in[4];
    const float* W1    = (const float*)d_in[5];
    const float* W2    = (const float*)d_in[6];
    const float* Whis  = (const float*)d_in[7];
    const float* WT    = (const float*)d_in[8];

    float* out = (float*)d_out;
    float* h1o = out;                                  // h1  [N, D]
    float* h2o = out + (size_t)N_NODES * D_DIM;        // h2  [N, D]
    float* fo  = out + 2 * (size_t)N_NODES * D_DIM;    // feat [N, D]

    // h1 = sage(feats, idx1, W1)
    sage_f32<25, false><<<N_NODES, 128, 0, stream>>>(feats, feats, idx1, W1, h1o, nullptr);
    // f1 = temporal(h1[:NUM], hist1) -> staged in feat rows [0, NUM)
    temporal_f32<<<NUM_P, 128, 0, stream>>>(h1o, hist1, Whis, WT, fo);
    // h2 = sage(h1_copy, idx2, W2); rows >= NUM mirrored into feat tail
    sage_f32<10, true><<<N_NODES, 128, 0, stream>>>(fo, h1o, idx2, W2, h2o, fo);
    // f2 = temporal(h2[:NUM], hist2) -> feat rows [0, NUM), overwrites f1
    temporal_f32<<<NUM_P, 128, 0, stream>>>(h2o, hist2, Whis, WT, fo);
}

// Round 5
// 306.095 us; speedup vs baseline: 2.2005x; 2.2005x over previous
//
#include <hip/hip_runtime.h>

#define N_NODES 50000
#define NUM_P   20000
#define D_DIM   128
#define ALPHA_  0.2f
#define EPS_    1e-12f
#define NT      16      // nodes per block (50000 = 3125*16, 20000 = 1250*16)

// ---------------------------------------------------------------------------
// SAGE: out0[node] = l2norm(leaky([x[node] | mean_k x[idx[node,k]]] @ W))
// 16 nodes per 256-thread block. SPLIT: row r < NUM_P -> srcLow else srcHigh.
// out1 (optional): also write rows >= NUM_P there (feat tail).
// ---------------------------------------------------------------------------
template<int K, bool SPLIT>
__global__ __launch_bounds__(256)
void sage_v5(const float* __restrict__ srcLow,
             const float* __restrict__ srcHigh,
             const int*   __restrict__ idx,
             const float* __restrict__ W,      // [2D][D] row-major
             float* __restrict__ out0,
             float* __restrict__ out1)
{
    __shared__ float xs[NT][2 * D_DIM];   // [n][0:128]=self, [128:256]=neigh-mean
    __shared__ int   sidx[NT * K];
    __shared__ float rnorm[NT];

    const int tid  = threadIdx.x;
    const int base = blockIdx.x * NT;

    // stage indices (rows are contiguous: [base*K, base*K + NT*K))
    for (int i = tid; i < NT * K; i += 256)
        sidx[i] = idx[(size_t)base * K + i];
    __syncthreads();

    // ---- phase 1: gather. 8 groups of 32 lanes; group gp does nodes gp, gp+8.
    {
        const int gp = tid >> 5;
        const int l  = tid & 31;
        for (int n = gp; n < NT; n += 8) {
            const int node = base + n;
            const float* sp = (!SPLIT || node < NUM_P) ? srcLow : srcHigh;
            const float4 s4 = reinterpret_cast<const float4*>(sp + (size_t)node * D_DIM)[l];
            float4 a4 = make_float4(0.f, 0.f, 0.f, 0.f);
            for (int k = 0; k < K; ++k) {
                const int r = sidx[n * K + k];
                const float* rp = (!SPLIT || r < NUM_P) ? srcLow : srcHigh;
                const float4 v4 = reinterpret_cast<const float4*>(rp + (size_t)r * D_DIM)[l];
                a4.x += v4.x; a4.y += v4.y; a4.z += v4.z; a4.w += v4.w;
            }
            const float s = 1.0f / (float)K;
            float4 m4; m4.x = a4.x * s; m4.y = a4.y * s; m4.z = a4.z * s; m4.w = a4.w * s;
            reinterpret_cast<float4*>(&xs[n][0])[l]     = s4;
            reinterpret_cast<float4*>(&xs[n][D_DIM])[l] = m4;
        }
    }
    __syncthreads();

    // ---- phase 2: y = X @ W. Thread owns column j for 8 nodes.
    const int j  = tid & 127;
    const int g  = tid >> 7;
    const int nb = g * 8;

    float acc[8];
    #pragma unroll
    for (int r = 0; r < 8; ++r) acc[r] = 0.f;

    for (int c4 = 0; c4 < (2 * D_DIM) / 4; ++c4) {
        const int c = c4 * 4;
        const float w0 = W[(size_t)(c + 0) * D_DIM + j];
        const float w1 = W[(size_t)(c + 1) * D_DIM + j];
        const float w2 = W[(size_t)(c + 2) * D_DIM + j];
        const float w3 = W[(size_t)(c + 3) * D_DIM + j];
        #pragma unroll
        for (int r = 0; r < 8; ++r) {
            const float4 xv = *reinterpret_cast<const float4*>(&xs[nb + r][c]);
            acc[r] = fmaf(xv.w, w3, fmaf(xv.z, w2, fmaf(xv.y, w1, fmaf(xv.x, w0, acc[r]))));
        }
    }
    __syncthreads();   // done reading xs

    // ---- leaky, stash activations
    #pragma unroll
    for (int r = 0; r < 8; ++r) {
        float v = acc[r];
        v = v > 0.f ? v : ALPHA_ * v;
        xs[nb + r][j] = v;
    }
    __syncthreads();

    // ---- row norms: 16 lanes per node
    {
        const int n  = tid >> 4;
        const int ll = tid & 15;
        float s = 0.f;
        #pragma unroll
        for (int jj = ll; jj < D_DIM; jj += 16) { const float t = xs[n][jj]; s += t * t; }
        #pragma unroll
        for (int o = 8; o > 0; o >>= 1) s += __shfl_xor(s, o);
        if (ll == 0) rnorm[n] = 1.0f / fmaxf(sqrtf(s), EPS_);
    }
    __syncthreads();

    // ---- normalize + write
    #pragma unroll
    for (int r = 0; r < 8; ++r) {
        const int n    = nb + r;
        const int node = base + n;
        const float v  = xs[n][j] * rnorm[n];
        out0[(size_t)node * D_DIM + j] = v;
        if (out1 != nullptr && node >= NUM_P) out1[(size_t)node * D_DIM + j] = v;
    }
}

// ---------------------------------------------------------------------------
// Temporal: out[n] = l2norm(leaky([head[n] | ((mean_p hist[p,n]) @ Whis)] @ WT))
// 16 nodes per 256-thread block, nodes < NUM_P.
// ---------------------------------------------------------------------------
__global__ __launch_bounds__(256)
void temporal_v5(const float* __restrict__ head,   // rows < NUM_P used
                 const float* __restrict__ hist,   // [3][NUM_P][D]
                 const float* __restrict__ Whis,   // [D][D]
                 const float* __restrict__ WT,     // [2D][D]
                 float* __restrict__ outp)
{
    __shared__ float xs[NT][2 * D_DIM];   // [n][0:128]=head, [128:256]=tf
    __shared__ float hm[NT][D_DIM];       // hist mean
    __shared__ float rnorm[NT];

    const int tid  = threadIdx.x;
    const int base = blockIdx.x * NT;
    const size_t HS = (size_t)NUM_P * D_DIM;

    // ---- phase 1: head + hist mean (float4 streams)
    {
        const int gp = tid >> 5;
        const int l  = tid & 31;
        for (int n = gp; n < NT; n += 8) {
            const size_t off = (size_t)(base + n) * D_DIM;
            const float4 h4 = reinterpret_cast<const float4*>(head + off)[l];
            const float4 p0 = reinterpret_cast<const float4*>(hist + off)[l];
            const float4 p1 = reinterpret_cast<const float4*>(hist + off + HS)[l];
            const float4 p2 = reinterpret_cast<const float4*>(hist + off + 2 * HS)[l];
            float4 m4;
            m4.x = (p0.x + p1.x + p2.x) * (1.0f / 3.0f);
            m4.y = (p0.y + p1.y + p2.y) * (1.0f / 3.0f);
            m4.z = (p0.z + p1.z + p2.z) * (1.0f / 3.0f);
            m4.w = (p0.w + p1.w + p2.w) * (1.0f / 3.0f);
            reinterpret_cast<float4*>(&xs[n][0])[l] = h4;
            reinterpret_cast<float4*>(&hm[n][0])[l] = m4;
        }
    }
    __syncthreads();

    const int j  = tid & 127;
    const int g  = tid >> 7;
    const int nb = g * 8;

    // ---- phase 1b: tf = hm @ Whis
    {
        float a2[8];
        #pragma unroll
        for (int r = 0; r < 8; ++r) a2[r] = 0.f;
        for (int c4 = 0; c4 < D_DIM / 4; ++c4) {
            const int c = c4 * 4;
            const float w0 = Whis[(size_t)(c + 0) * D_DIM + j];
            const float w1 = Whis[(size_t)(c + 1) * D_DIM + j];
            const float w2 = Whis[(size_t)(c + 2) * D_DIM + j];
            const float w3 = Whis[(size_t)(c + 3) * D_DIM + j];
            #pragma unroll
            for (int r = 0; r < 8; ++r) {
                const float4 xv = *reinterpret_cast<const float4*>(&hm[nb + r][c]);
                a2[r] = fmaf(xv.w, w3, fmaf(xv.z, w2, fmaf(xv.y, w1, fmaf(xv.x, w0, a2[r]))));
            }
        }
        __syncthreads();   // hm reads done (not strictly needed, xs[*][128:] is disjoint from hm)
        #pragma unroll
        for (int r = 0; r < 8; ++r) xs[nb + r][D_DIM + j] = a2[r];
    }
    __syncthreads();

    // ---- phase 2: y = [head | tf] @ WT
    float acc[8];
    #pragma unroll
    for (int r = 0; r < 8; ++r) acc[r] = 0.f;
    for (int c4 = 0; c4 < (2 * D_DIM) / 4; ++c4) {
        const int c = c4 * 4;
        const float w0 = WT[(size_t)(c + 0) * D_DIM + j];
        const float w1 = WT[(size_t)(c + 1) * D_DIM + j];
        const float w2 = WT[(size_t)(c + 2) * D_DIM + j];
        const float w3 = WT[(size_t)(c + 3) * D_DIM + j];
        #pragma unroll
        for (int r = 0; r < 8; ++r) {
            const float4 xv = *reinterpret_cast<const float4*>(&xs[nb + r][c]);
            acc[r] = fmaf(xv.w, w3, fmaf(xv.z, w2, fmaf(xv.y, w1, fmaf(xv.x, w0, acc[r]))));
        }
    }
    __syncthreads();

    #pragma unroll
    for (int r = 0; r < 8; ++r) {
        float v = acc[r];
        v = v > 0.f ? v : ALPHA_ * v;
        xs[nb + r][j] = v;
    }
    __syncthreads();

    {
        const int n  = tid >> 4;
        const int ll = tid & 15;
        float s = 0.f;
        #pragma unroll
        for (int jj = ll; jj < D_DIM; jj += 16) { const float t = xs[n][jj]; s += t * t; }
        #pragma unroll
        for (int o = 8; o > 0; o >>= 1) s += __shfl_xor(s, o);
        if (ll == 0) rnorm[n] = 1.0f / fmaxf(sqrtf(s), EPS_);
    }
    __syncthreads();

    #pragma unroll
    for (int r = 0; r < 8; ++r) {
        const int n = nb + r;
        outp[(size_t)(base + n) * D_DIM + j] = xs[n][j] * rnorm[n];
    }
}

// ---------------------------------------------------------------------------
extern "C" void kernel_launch(void* const* d_in, const int* in_sizes, int n_in,
                              void* d_out, int out_size, void* d_ws, size_t ws_size,
                              hipStream_t stream)
{
    (void)in_sizes; (void)n_in; (void)out_size; (void)d_ws; (void)ws_size;

    const float* feats = (const float*)d_in[0];
    const int*   idx1  = (const int*)  d_in[1];
    const int*   idx2  = (const int*)  d_in[2];
    const float* hist1 = (const float*)d_in[3];
    const float* hist2 = (const float*)d_in[4];
    const float* W1    = (const float*)d_in[5];
    const float* W2    = (const float*)d_in[6];
    const float* Whis  = (const float*)d_in[7];
    const float* WT    = (const float*)d_in[8];

    float* out = (float*)d_out;
    float* h1o = out;                                  // h1  [N, D]
    float* h2o = out + (size_t)N_NODES * D_DIM;        // h2  [N, D]
    float* fo  = out + 2 * (size_t)N_NODES * D_DIM;    // feat [N, D]

    const int sage_blocks = N_NODES / NT;  // 3125
    const int temp_blocks = NUM_P   / NT;  // 1250

    // h1 = sage(feats, idx1, W1)
    sage_v5<25, false><<<sage_blocks, 256, 0, stream>>>(feats, feats, idx1, W1, h1o, nullptr);
    // f1 = temporal(h1[:NUM], hist1) -> staged in feat rows [0, NUM)
    temporal_v5<<<temp_blocks, 256, 0, stream>>>(h1o, hist1, Whis, WT, fo);
    // h2 = sage(h1_copy, idx2, W2); rows >= NUM mirrored into feat tail
    // (reads fo rows [0,NUM) and h1o; writes fo rows [NUM,N) — disjoint)
    sage_v5<10, true><<<sage_blocks, 256, 0, stream>>>(fo, h1o, idx2, W2, h2o, fo);
    // f2 = temporal(h2[:NUM], hist2) -> feat rows [0, NUM), overwrites f1
    temporal_v5<<<temp_blocks, 256, 0, stream>>>(h2o, hist2, Whis, WT, fo);
}